// Round 1
// baseline (470.348 us; speedup 1.0000x reference)
//
#include <hip/hip_runtime.h>

#define NPIX 49152   // B*H*W = 1*192*256
#define H_ 192
#define W_ 256

// ---------------------------------------------------------------------------
// conv 128->128 (1x1): Y[o][p] = act(sum_k W[o][k] * X[k][p] + B[o])
// Block: 256 threads = 4 wave-groups x 64 pixels. LDS-staged X tile (32 KB).
// Weight index is wave-uniform (og = t>>6 constant per wave) -> scalar loads.
// ---------------------------------------------------------------------------
template<bool ACT>
__global__ __launch_bounds__(256) void conv128_k(const float* __restrict__ X,
    const float* __restrict__ W, const float* __restrict__ Bv,
    float* __restrict__ Y) {
  __shared__ float xs[128][64];
  const int t = threadIdx.x;
  const int p0 = blockIdx.x * 64;
  for (int i = t; i < 128 * 64; i += 256) {
    xs[i >> 6][i & 63] = X[(i >> 6) * NPIX + p0 + (i & 63)];
  }
  __syncthreads();
  const int og = t >> 6;      // 0..3, constant within a wave
  const int pl = t & 63;      // pixel within tile
  const float* __restrict__ Wg = W + og * 32 * 128;
  float acc[32];
#pragma unroll
  for (int o = 0; o < 32; ++o) acc[o] = Bv[og * 32 + o];
  for (int k0 = 0; k0 < 128; k0 += 8) {
    float xv[8];
#pragma unroll
    for (int kk = 0; kk < 8; ++kk) xv[kk] = xs[k0 + kk][pl];
#pragma unroll
    for (int o = 0; o < 32; ++o) {
#pragma unroll
      for (int kk = 0; kk < 8; ++kk)
        acc[o] = fmaf(xv[kk], Wg[o * 128 + k0 + kk], acc[o]);
    }
  }
#pragma unroll
  for (int o = 0; o < 32; ++o) {
    float v = acc[o];
    if (ACT) v = v > 0.f ? v : 0.01f * v;
    Y[(og * 32 + o) * NPIX + p0 + pl] = v;
  }
}

// ---------------------------------------------------------------------------
// conv 128->17 + argmax(first 16, first-max-wins) + mask = lrelu(ch 16).
// inds1 stored in pixel-flat order (h*W+w), matching reference reshape(-1).
// ---------------------------------------------------------------------------
__global__ __launch_bounds__(256) void conv17_k(const float* __restrict__ X,
    const float* __restrict__ W, const float* __restrict__ Bv,
    int* __restrict__ inds1, float* __restrict__ mask_out) {
  const int p = blockIdx.x * 256 + threadIdx.x;
  float acc[17];
#pragma unroll
  for (int o = 0; o < 17; ++o) acc[o] = Bv[o];
  for (int k0 = 0; k0 < 128; k0 += 8) {
    float xv[8];
#pragma unroll
    for (int kk = 0; kk < 8; ++kk) xv[kk] = X[(k0 + kk) * NPIX + p];
#pragma unroll
    for (int o = 0; o < 17; ++o) {
#pragma unroll
      for (int kk = 0; kk < 8; ++kk)
        acc[o] = fmaf(xv[kk], W[o * 128 + k0 + kk], acc[o]);
    }
  }
  int am = 0;
  float bv = acc[0];
#pragma unroll
  for (int o = 1; o < 16; ++o) {
    if (acc[o] > bv) { bv = acc[o]; am = o; }   // strict > keeps first max
  }
  inds1[p] = am;
  const float m = acc[16];
  mask_out[p] = m > 0.f ? m : 0.01f * m;
}

// ---------------------------------------------------------------------------
// Fused routing: both cond_mul chains per token.
// Thread p <-> token n = (p%W)*H + p/W, so x_in reads at pixel p are
// coalesced; inds1 gather at [n] and output scatter at [n] faithfully
// reproduce the reference's (W,H)-vs-(H,W) flatten mixing.
// ---------------------------------------------------------------------------
__global__ __launch_bounds__(256) void routing_k(const float* __restrict__ X,
    const int* __restrict__ inds1,
    const float* __restrict__ wc21, const float* __restrict__ bc21,
    const float* __restrict__ wc22, const float* __restrict__ bc22,
    const float* __restrict__ wc23, const float* __restrict__ bc23,
    const float* __restrict__ wr11, const float* __restrict__ br11,
    const float* __restrict__ wr12, const float* __restrict__ br12,
    const float* __restrict__ wr13, const float* __restrict__ br13,
    float* __restrict__ out) {
  const int p = blockIdx.x * 256 + threadIdx.x;
  const int h = p >> 8;          // p / W  (W=256)
  const int w = p & 255;         // p % W
  const int n = w * H_ + h;      // token index (B,W,H flatten order)
  const int e1 = inds1[n];

  float a[32];   // layer-1 / chain2-layer-1 accumulator
  float b2[32];  // chain1 layer-2
  float s[16];   // chain1 layer-3 logits / chain2 layer-2

  // ---- chain 1, layer 1: 128 -> 32 ----
  {
    const float* __restrict__ W1 = wc21 + e1 * (128 * 32);
    const float* __restrict__ B1 = bc21 + e1 * 32;
#pragma unroll
    for (int o = 0; o < 32; ++o) a[o] = B1[o];
#pragma unroll 4
    for (int k = 0; k < 128; ++k) {
      const float xv = X[k * NPIX + p];
      const float4* __restrict__ Wr = (const float4*)(W1 + k * 32);
#pragma unroll
      for (int q = 0; q < 8; ++q) {
        const float4 wv = Wr[q];
        a[4 * q + 0] = fmaf(xv, wv.x, a[4 * q + 0]);
        a[4 * q + 1] = fmaf(xv, wv.y, a[4 * q + 1]);
        a[4 * q + 2] = fmaf(xv, wv.z, a[4 * q + 2]);
        a[4 * q + 3] = fmaf(xv, wv.w, a[4 * q + 3]);
      }
    }
#pragma unroll
    for (int o = 0; o < 32; ++o) a[o] = a[o] > 0.f ? a[o] : 0.01f * a[o];
  }

  // ---- chain 1, layer 2: 32 -> 32 ----
  {
    const float* __restrict__ W2 = wc22 + e1 * 1024;
    const float* __restrict__ B2 = bc22 + e1 * 32;
#pragma unroll
    for (int o = 0; o < 32; ++o) b2[o] = B2[o];
#pragma unroll 4
    for (int i = 0; i < 32; ++i) {
      const float hv = a[i];
      const float4* __restrict__ Wr = (const float4*)(W2 + i * 32);
#pragma unroll
      for (int q = 0; q < 8; ++q) {
        const float4 wv = Wr[q];
        b2[4 * q + 0] = fmaf(hv, wv.x, b2[4 * q + 0]);
        b2[4 * q + 1] = fmaf(hv, wv.y, b2[4 * q + 1]);
        b2[4 * q + 2] = fmaf(hv, wv.z, b2[4 * q + 2]);
        b2[4 * q + 3] = fmaf(hv, wv.w, b2[4 * q + 3]);
      }
    }
#pragma unroll
    for (int o = 0; o < 32; ++o) b2[o] = b2[o] > 0.f ? b2[o] : 0.01f * b2[o];
  }

  // ---- chain 1, layer 3: 32 -> 16 (logits) ----
  {
    const float* __restrict__ W3 = wc23 + e1 * 512;
    const float* __restrict__ B3 = bc23 + e1 * 16;
#pragma unroll
    for (int o = 0; o < 16; ++o) s[o] = B3[o];
#pragma unroll 4
    for (int i = 0; i < 32; ++i) {
      const float hv = b2[i];
      const float4* __restrict__ Wr = (const float4*)(W3 + i * 16);
#pragma unroll
      for (int q = 0; q < 4; ++q) {
        const float4 wv = Wr[q];
        s[4 * q + 0] = fmaf(hv, wv.x, s[4 * q + 0]);
        s[4 * q + 1] = fmaf(hv, wv.y, s[4 * q + 1]);
        s[4 * q + 2] = fmaf(hv, wv.z, s[4 * q + 2]);
        s[4 * q + 3] = fmaf(hv, wv.w, s[4 * q + 3]);
      }
    }
  }
  int e2 = 0;
  {
    float bv = s[0];
#pragma unroll
    for (int o = 1; o < 16; ++o) {
      if (s[o] > bv) { bv = s[o]; e2 = o; }
    }
  }
  const int e12 = e1 * 16 + e2;

  // ---- chain 2, layer 1: 128 -> 32 ----
  {
    const float* __restrict__ W1 = wr11 + e12 * (128 * 32);
    const float* __restrict__ B1 = br11 + e12 * 32;
#pragma unroll
    for (int o = 0; o < 32; ++o) a[o] = B1[o];
#pragma unroll 4
    for (int k = 0; k < 128; ++k) {
      const float xv = X[k * NPIX + p];
      const float4* __restrict__ Wr = (const float4*)(W1 + k * 32);
#pragma unroll
      for (int q = 0; q < 8; ++q) {
        const float4 wv = Wr[q];
        a[4 * q + 0] = fmaf(xv, wv.x, a[4 * q + 0]);
        a[4 * q + 1] = fmaf(xv, wv.y, a[4 * q + 1]);
        a[4 * q + 2] = fmaf(xv, wv.z, a[4 * q + 2]);
        a[4 * q + 3] = fmaf(xv, wv.w, a[4 * q + 3]);
      }
    }
#pragma unroll
    for (int o = 0; o < 32; ++o) a[o] = a[o] > 0.f ? a[o] : 0.01f * a[o];
  }

  // ---- chain 2, layer 2: 32 -> 16 ----
  {
    const float* __restrict__ W2 = wr12 + e12 * 512;
    const float* __restrict__ B2 = br12 + e12 * 16;
#pragma unroll
    for (int o = 0; o < 16; ++o) s[o] = B2[o];
#pragma unroll 4
    for (int i = 0; i < 32; ++i) {
      const float hv = a[i];
      const float4* __restrict__ Wr = (const float4*)(W2 + i * 16);
#pragma unroll
      for (int q = 0; q < 4; ++q) {
        const float4 wv = Wr[q];
        s[4 * q + 0] = fmaf(hv, wv.x, s[4 * q + 0]);
        s[4 * q + 1] = fmaf(hv, wv.y, s[4 * q + 1]);
        s[4 * q + 2] = fmaf(hv, wv.z, s[4 * q + 2]);
        s[4 * q + 3] = fmaf(hv, wv.w, s[4 * q + 3]);
      }
    }
#pragma unroll
    for (int o = 0; o < 16; ++o) s[o] = s[o] > 0.f ? s[o] : 0.01f * s[o];
  }

  // ---- chain 2, layer 3: 16 -> 1 ----
  float r = br13[e12];
  {
    const float* __restrict__ W3 = wr13 + e12 * 16;
#pragma unroll
    for (int i = 0; i < 16; ++i) r = fmaf(s[i], W3[i], r);
  }

  out[n] = ((float)e12 + r) * (1.0f / 256.0f);
}

// ---------------------------------------------------------------------------
extern "C" void kernel_launch(void* const* d_in, const int* in_sizes, int n_in,
                              void* d_out, int out_size, void* d_ws,
                              size_t ws_size, hipStream_t stream) {
  const float* x_in  = (const float*)d_in[0];
  const float* w_c11 = (const float*)d_in[1];
  const float* b_c11 = (const float*)d_in[2];
  const float* w_c12 = (const float*)d_in[3];
  const float* b_c12 = (const float*)d_in[4];
  const float* w_c13 = (const float*)d_in[5];
  const float* b_c13 = (const float*)d_in[6];
  const float* w_c21 = (const float*)d_in[7];
  const float* b_c21 = (const float*)d_in[8];
  const float* w_c22 = (const float*)d_in[9];
  const float* b_c22 = (const float*)d_in[10];
  const float* w_c23 = (const float*)d_in[11];
  const float* b_c23 = (const float*)d_in[12];
  const float* w_r11 = (const float*)d_in[13];
  const float* b_r11 = (const float*)d_in[14];
  const float* w_r12 = (const float*)d_in[15];
  const float* b_r12 = (const float*)d_in[16];
  const float* w_r13 = (const float*)d_in[17];
  const float* b_r13 = (const float*)d_in[18];

  float* out = (float*)d_out;          // [0..N): x_real (token order), [N..2N): mask (pixel order)

  float* y1 = (float*)d_ws;                    // 128*N floats
  float* y2 = y1 + 128 * NPIX;                 // 128*N floats
  int* inds1 = (int*)(y2 + 128 * NPIX);        // N ints

  conv128_k<true><<<NPIX / 64, 256, 0, stream>>>(x_in, w_c11, b_c11, y1);
  conv128_k<true><<<NPIX / 64, 256, 0, stream>>>(y1, w_c12, b_c12, y2);
  conv17_k<<<NPIX / 256, 256, 0, stream>>>(y2, w_c13, b_c13, inds1, out + NPIX);
  routing_k<<<NPIX / 256, 256, 0, stream>>>(x_in, inds1,
      w_c21, b_c21, w_c22, b_c22, w_c23, b_c23,
      w_r11, b_r11, w_r12, b_r12, w_r13, b_r13, out);
}

// Round 2
// 372.017 us; speedup vs baseline: 1.2643x; 1.2643x over previous
//
#include <hip/hip_runtime.h>

#define NPIX 49152   // B*H*W = 1*192*256
#define H_ 192
#define W_ 256
#define TPB 64       // tokens per chain block (1 wave)

// ---------------------------------------------------------------------------
// conv 128->128 (1x1): Y[o][p] = act(sum_k W[o][k] * X[k][p] + B[o])
// ---------------------------------------------------------------------------
template<bool ACT>
__global__ __launch_bounds__(256) void conv128_k(const float* __restrict__ X,
    const float* __restrict__ W, const float* __restrict__ Bv,
    float* __restrict__ Y) {
  __shared__ float xs[128][64];
  const int t = threadIdx.x;
  const int p0 = blockIdx.x * 64;
  for (int i = t; i < 128 * 64; i += 256) {
    xs[i >> 6][i & 63] = X[(i >> 6) * NPIX + p0 + (i & 63)];
  }
  __syncthreads();
  const int og = t >> 6;
  const int pl = t & 63;
  const float* __restrict__ Wg = W + og * 32 * 128;
  float acc[32];
#pragma unroll
  for (int o = 0; o < 32; ++o) acc[o] = Bv[og * 32 + o];
  for (int k0 = 0; k0 < 128; k0 += 8) {
    float xv[8];
#pragma unroll
    for (int kk = 0; kk < 8; ++kk) xv[kk] = xs[k0 + kk][pl];
#pragma unroll
    for (int o = 0; o < 32; ++o) {
#pragma unroll
      for (int kk = 0; kk < 8; ++kk)
        acc[o] = fmaf(xv[kk], Wg[o * 128 + k0 + kk], acc[o]);
    }
  }
#pragma unroll
  for (int o = 0; o < 32; ++o) {
    float v = acc[o];
    if (ACT) v = v > 0.f ? v : 0.01f * v;
    Y[(og * 32 + o) * NPIX + p0 + pl] = v;
  }
}

// ---------------------------------------------------------------------------
// conv 128->17 + argmax(first 16) + mask = lrelu(ch 16). inds1 pixel-order.
// ---------------------------------------------------------------------------
__global__ __launch_bounds__(256) void conv17_k(const float* __restrict__ X,
    const float* __restrict__ W, const float* __restrict__ Bv,
    int* __restrict__ inds1, float* __restrict__ mask_out) {
  const int p = blockIdx.x * 256 + threadIdx.x;
  float acc[17];
#pragma unroll
  for (int o = 0; o < 17; ++o) acc[o] = Bv[o];
  for (int k0 = 0; k0 < 128; k0 += 8) {
    float xv[8];
#pragma unroll
    for (int kk = 0; kk < 8; ++kk) xv[kk] = X[(k0 + kk) * NPIX + p];
#pragma unroll
    for (int o = 0; o < 17; ++o) {
#pragma unroll
      for (int kk = 0; kk < 8; ++kk)
        acc[o] = fmaf(xv[kk], W[o * 128 + k0 + kk], acc[o]);
    }
  }
  int am = 0;
  float bv = acc[0];
#pragma unroll
  for (int o = 1; o < 16; ++o) {
    if (acc[o] > bv) { bv = acc[o]; am = o; }
  }
  inds1[p] = am;
  const float m = acc[16];
  mask_out[p] = m > 0.f ? m : 0.01f * m;
}

// ---------------------------------------------------------------------------
// transpose x[k][h][w] -> xt[(w*H+h)*128 + k]  (token-major feature rows)
// ---------------------------------------------------------------------------
__global__ __launch_bounds__(256) void transpose_k(const float* __restrict__ X,
                                                   float* __restrict__ xt) {
  __shared__ float tile[32][33];
  const int w0 = (blockIdx.x & 7) * 32;
  const int k0 = ((blockIdx.x >> 3) & 3) * 32;
  const int h  = blockIdx.x >> 5;          // 0..191
  const int t = threadIdx.x;
  const int c = t & 31, rr = t >> 5;
#pragma unroll
  for (int j = 0; j < 4; ++j) {
    const int k = rr + j * 8;
    tile[k][c] = X[(k0 + k) * NPIX + h * W_ + w0 + c];
  }
  __syncthreads();
#pragma unroll
  for (int j = 0; j < 4; ++j) {
    const int w = rr + j * 8;
    xt[((w0 + w) * H_ + h) * 128 + k0 + c] = tile[c][w];
  }
}

// ---------------------------------------------------------------------------
__global__ __launch_bounds__(256) void init_k(int* __restrict__ a, int na,
                                              int* __restrict__ b, int nb) {
  const int t = threadIdx.x;
  for (int i = t; i < na; i += 256) a[i] = 0;
  for (int i = t; i < nb; i += 256) b[i] = 0;
}

__global__ __launch_bounds__(256) void hist_k(const int* __restrict__ bins,
                                              int* __restrict__ cnt) {
  __shared__ int lh[256];
  const int t = threadIdx.x;
  lh[t] = 0;
  __syncthreads();
  atomicAdd(&lh[bins[blockIdx.x * 256 + t]], 1);
  __syncthreads();
  if (lh[t] > 0) atomicAdd(&cnt[t], lh[t]);
}

template<int NB>
__global__ __launch_bounds__(256) void scan_desc_k(const int* __restrict__ cnt,
    int* __restrict__ off, int* __restrict__ desc, int* __restrict__ ndesc) {
  __shared__ int loff[NB];
  __shared__ int ldesc[1024];
  __shared__ int lnd;
  if (threadIdx.x == 0) {
    int acc = 0, d = 0;
    for (int e = 0; e < NB; ++e) {
      loff[e] = acc;
      const int c = cnt[e];
      acc += c;
      const int nb = (c + TPB - 1) / TPB;
      for (int j = 0; j < nb; ++j) ldesc[d++] = (e << 12) | j;
    }
    lnd = d;
  }
  __syncthreads();
  for (int i = threadIdx.x; i < NB; i += 256) off[i] = loff[i];
  const int nd = lnd;
  for (int i = threadIdx.x; i < nd; i += 256) desc[i] = ldesc[i];
  if (threadIdx.x == 0) *ndesc = nd;
}

// two-level scatter: block-local ranks + one global atomic per (block,bin)
__global__ __launch_bounds__(256) void scatter_k(const int* __restrict__ bins,
    const int* __restrict__ off, int* __restrict__ cursor,
    int* __restrict__ ord, int nbins) {
  __shared__ int lhist[256], lbase[256], lcur[256];
  const int t = threadIdx.x;
  const int n = blockIdx.x * 256 + t;
  if (t < nbins) { lhist[t] = 0; lcur[t] = 0; }
  __syncthreads();
  const int b = bins[n];
  atomicAdd(&lhist[b], 1);
  __syncthreads();
  if (t < nbins && lhist[t] > 0) lbase[t] = atomicAdd(&cursor[t], lhist[t]);
  __syncthreads();
  const int r = atomicAdd(&lcur[b], 1);
  ord[off[b] + lbase[b] + r] = n;
}

// ---------------------------------------------------------------------------
// chain1: uniform expert e1 per block (scalar weight loads). Computes e12,
// fused histogram into cnt2.
// ---------------------------------------------------------------------------
__global__ __launch_bounds__(64) void chain1_k(const float* __restrict__ xt,
    const int* __restrict__ ord1, const int* __restrict__ off1,
    const int* __restrict__ cnt1, const int* __restrict__ desc1,
    const int* __restrict__ nd1,
    const float* __restrict__ wc21, const float* __restrict__ bc21,
    const float* __restrict__ wc22, const float* __restrict__ bc22,
    const float* __restrict__ wc23, const float* __restrict__ bc23,
    int* __restrict__ e12a, int* __restrict__ cnt2) {
  if ((int)blockIdx.x >= *nd1) return;
  __shared__ int lh[16];
  const int de = desc1[blockIdx.x];
  const int e = de >> 12, chunk = de & 0xFFF;
  const int cnt = cnt1[e];
  const int pos = chunk * TPB + (int)threadIdx.x;
  const bool valid = pos < cnt;
  const int n = valid ? ord1[off1[e] + pos] : 0;
  if (threadIdx.x < 16) lh[threadIdx.x] = 0;
  __syncthreads();
  const float* __restrict__ xr = xt + n * 128;

  // L1: 128 -> 32
  const float* __restrict__ W1 = wc21 + e * 4096;
  const float* __restrict__ B1 = bc21 + e * 32;
  float a[32];
#pragma unroll
  for (int o = 0; o < 32; ++o) a[o] = B1[o];
  for (int k0 = 0; k0 < 128; k0 += 8) {
    float x[8];
#pragma unroll
    for (int q = 0; q < 2; ++q) {
      const float4 v = ((const float4*)(xr + k0))[q];
      x[4*q] = v.x; x[4*q+1] = v.y; x[4*q+2] = v.z; x[4*q+3] = v.w;
    }
#pragma unroll
    for (int kk = 0; kk < 8; ++kk)
#pragma unroll
      for (int o = 0; o < 32; ++o)
        a[o] = fmaf(x[kk], W1[(k0 + kk) * 32 + o], a[o]);
  }
#pragma unroll
  for (int o = 0; o < 32; ++o) a[o] = a[o] > 0.f ? a[o] : 0.01f * a[o];

  // L2: 32 -> 32
  const float* __restrict__ W2 = wc22 + e * 1024;
  const float* __restrict__ B2 = bc22 + e * 32;
  float b[32];
#pragma unroll
  for (int o = 0; o < 32; ++o) b[o] = B2[o];
#pragma unroll
  for (int i = 0; i < 32; ++i)
#pragma unroll
    for (int o = 0; o < 32; ++o)
      b[o] = fmaf(a[i], W2[i * 32 + o], b[o]);
#pragma unroll
  for (int o = 0; o < 32; ++o) b[o] = b[o] > 0.f ? b[o] : 0.01f * b[o];

  // L3: 32 -> 16 (logits)
  const float* __restrict__ W3 = wc23 + e * 512;
  const float* __restrict__ B3 = bc23 + e * 16;
  float s[16];
#pragma unroll
  for (int o = 0; o < 16; ++o) s[o] = B3[o];
#pragma unroll
  for (int i = 0; i < 32; ++i)
#pragma unroll
    for (int o = 0; o < 16; ++o)
      s[o] = fmaf(b[i], W3[i * 16 + o], s[o]);

  int e2 = 0;
  float bv = s[0];
#pragma unroll
  for (int o = 1; o < 16; ++o) {
    if (s[o] > bv) { bv = s[o]; e2 = o; }
  }
  const int e12 = e * 16 + e2;
  if (valid) {
    e12a[n] = e12;
    atomicAdd(&lh[e2], 1);
  }
  __syncthreads();
  if (threadIdx.x < 16 && lh[threadIdx.x] > 0)
    atomicAdd(&cnt2[e * 16 + threadIdx.x], lh[threadIdx.x]);
}

// ---------------------------------------------------------------------------
// chain2: uniform expert e12 per block. Writes out[n].
// ---------------------------------------------------------------------------
__global__ __launch_bounds__(64) void chain2_k(const float* __restrict__ xt,
    const int* __restrict__ ord2, const int* __restrict__ off2,
    const int* __restrict__ cnt2, const int* __restrict__ desc2,
    const int* __restrict__ nd2,
    const float* __restrict__ wr11, const float* __restrict__ br11,
    const float* __restrict__ wr12, const float* __restrict__ br12,
    const float* __restrict__ wr13, const float* __restrict__ br13,
    float* __restrict__ out) {
  if ((int)blockIdx.x >= *nd2) return;
  const int de = desc2[blockIdx.x];
  const int e12 = de >> 12, chunk = de & 0xFFF;
  const int cnt = cnt2[e12];
  const int pos = chunk * TPB + (int)threadIdx.x;
  const bool valid = pos < cnt;
  const int n = valid ? ord2[off2[e12] + pos] : 0;
  const float* __restrict__ xr = xt + n * 128;

  // L1: 128 -> 32
  const float* __restrict__ W1 = wr11 + e12 * 4096;
  const float* __restrict__ B1 = br11 + e12 * 32;
  float a[32];
#pragma unroll
  for (int o = 0; o < 32; ++o) a[o] = B1[o];
  for (int k0 = 0; k0 < 128; k0 += 8) {
    float x[8];
#pragma unroll
    for (int q = 0; q < 2; ++q) {
      const float4 v = ((const float4*)(xr + k0))[q];
      x[4*q] = v.x; x[4*q+1] = v.y; x[4*q+2] = v.z; x[4*q+3] = v.w;
    }
#pragma unroll
    for (int kk = 0; kk < 8; ++kk)
#pragma unroll
      for (int o = 0; o < 32; ++o)
        a[o] = fmaf(x[kk], W1[(k0 + kk) * 32 + o], a[o]);
  }
#pragma unroll
  for (int o = 0; o < 32; ++o) a[o] = a[o] > 0.f ? a[o] : 0.01f * a[o];

  // L2: 32 -> 16
  const float* __restrict__ W2 = wr12 + e12 * 512;
  const float* __restrict__ B2 = br12 + e12 * 16;
  float s[16];
#pragma unroll
  for (int o = 0; o < 16; ++o) s[o] = B2[o];
#pragma unroll
  for (int i = 0; i < 32; ++i)
#pragma unroll
    for (int o = 0; o < 16; ++o)
      s[o] = fmaf(a[i], W2[i * 16 + o], s[o]);
#pragma unroll
  for (int o = 0; o < 16; ++o) s[o] = s[o] > 0.f ? s[o] : 0.01f * s[o];

  // L3: 16 -> 1
  float r = br13[e12];
  const float* __restrict__ W3 = wr13 + e12 * 16;
#pragma unroll
  for (int i = 0; i < 16; ++i) r = fmaf(s[i], W3[i], r);

  if (valid) out[n] = ((float)e12 + r) * (1.0f / 256.0f);
}

// ---------------------------------------------------------------------------
extern "C" void kernel_launch(void* const* d_in, const int* in_sizes, int n_in,
                              void* d_out, int out_size, void* d_ws,
                              size_t ws_size, hipStream_t stream) {
  const float* x_in  = (const float*)d_in[0];
  const float* w_c11 = (const float*)d_in[1];
  const float* b_c11 = (const float*)d_in[2];
  const float* w_c12 = (const float*)d_in[3];
  const float* b_c12 = (const float*)d_in[4];
  const float* w_c13 = (const float*)d_in[5];
  const float* b_c13 = (const float*)d_in[6];
  const float* w_c21 = (const float*)d_in[7];
  const float* b_c21 = (const float*)d_in[8];
  const float* w_c22 = (const float*)d_in[9];
  const float* b_c22 = (const float*)d_in[10];
  const float* w_c23 = (const float*)d_in[11];
  const float* b_c23 = (const float*)d_in[12];
  const float* w_r11 = (const float*)d_in[13];
  const float* b_r11 = (const float*)d_in[14];
  const float* w_r12 = (const float*)d_in[15];
  const float* b_r12 = (const float*)d_in[16];
  const float* w_r13 = (const float*)d_in[17];
  const float* b_r13 = (const float*)d_in[18];

  float* out = (float*)d_out;   // [0..N): x_real (token order), [N..2N): mask

  // ws layout (stays within round-1 footprint: 2*128N floats + N ints)
  float* y1 = (float*)d_ws;            // 128N floats; later reused as xt
  float* y2 = y1 + 128 * NPIX;         // 128N floats; later reused as int scratch
  int* inds1 = (int*)(y2 + 128 * NPIX);

  float* xt = y1;                      // alias: y1 dead after conv12
  int* ib    = (int*)y2;               // alias: y2 dead after conv17
  int* ord1  = ib;                     // N
  int* ord2  = ib + NPIX;              // N
  int* e12a  = ib + 2 * NPIX;          // N
  int* cnt1  = ib + 3 * NPIX;          // 16
  int* cur1  = cnt1 + 16;              // 16
  int* off1  = cur1 + 16;              // 16
  int* nd1   = off1 + 16;              // 1 (+pad)
  int* desc1 = nd1 + 16;               // 1024
  int* cnt2  = desc1 + 1024;           // 256
  int* cur2  = cnt2 + 256;             // 256
  int* off2  = cur2 + 256;             // 256
  int* nd2   = off2 + 256;             // 1 (+pad)
  int* desc2 = nd2 + 16;               // 1024

  conv128_k<true><<<NPIX / 64, 256, 0, stream>>>(x_in, w_c11, b_c11, y1);
  conv128_k<true><<<NPIX / 64, 256, 0, stream>>>(y1, w_c12, b_c12, y2);
  conv17_k<<<NPIX / 256, 256, 0, stream>>>(y2, w_c13, b_c13, inds1, out + NPIX);

  // y2 region now dead -> int scratch; y1 region dead -> xt
  init_k<<<1, 256, 0, stream>>>(cnt1, 32, cnt2, 512);   // zeros cnt1+cur1, cnt2+cur2
  transpose_k<<<192 * 32, 256, 0, stream>>>(x_in, xt);
  hist_k<<<NPIX / 256, 256, 0, stream>>>(inds1, cnt1);
  scan_desc_k<16><<<1, 256, 0, stream>>>(cnt1, off1, desc1, nd1);
  scatter_k<<<NPIX / 256, 256, 0, stream>>>(inds1, off1, cur1, ord1, 16);
  chain1_k<<<NPIX / TPB + 16, TPB, 0, stream>>>(xt, ord1, off1, cnt1, desc1, nd1,
      w_c21, b_c21, w_c22, b_c22, w_c23, b_c23, e12a, cnt2);
  scan_desc_k<256><<<1, 256, 0, stream>>>(cnt2, off2, desc2, nd2);
  scatter_k<<<NPIX / 256, 256, 0, stream>>>(e12a, off2, cur2, ord2, 256);
  chain2_k<<<NPIX / TPB + 256, TPB, 0, stream>>>(xt, ord2, off2, cnt2, desc2, nd2,
      w_r11, b_r11, w_r12, b_r12, w_r13, b_r13, out);
}

// Round 3
// 261.458 us; speedup vs baseline: 1.7989x; 1.4229x over previous
//
#include <hip/hip_runtime.h>

#define NPIX 49152   // B*H*W = 1*192*256
#define H_ 192
#define W_ 256
#define TPB 64       // tokens per chain block (1 wave)

// ---------------------------------------------------------------------------
// weight transpose 128x128: WT[k][o] = W[o][k]  (16 blocks of 32x32 tiles)
// ---------------------------------------------------------------------------
__global__ __launch_bounds__(256) void wtrans_k(const float* __restrict__ W,
                                                float* __restrict__ WT) {
  __shared__ float tile[32][33];
  const int bx = blockIdx.x & 3, by = blockIdx.x >> 2;
  const int c = threadIdx.x & 31, r0 = threadIdx.x >> 5;
#pragma unroll
  for (int j = 0; j < 4; ++j) {
    const int r = r0 + j * 8;
    tile[r][c] = W[(by * 32 + r) * 128 + bx * 32 + c];
  }
  __syncthreads();
#pragma unroll
  for (int j = 0; j < 4; ++j) {
    const int r = r0 + j * 8;
    WT[(bx * 32 + r) * 128 + by * 32 + c] = tile[c][r];
  }
}

// ---------------------------------------------------------------------------
// conv 128->128 as register-blocked GEMM.
// Block: 128 threads, tile 128 outputs x 64 pixels, micro-tile 8x8.
// Double-buffered LDS chunks of K=16 for both X and transposed W.
// Accumulation order: bias, then k ascending — bitwise-identical to the
// previous version (keeps argmax decisions stable across rounds).
// ---------------------------------------------------------------------------
template<bool ACT>
__global__ __launch_bounds__(128) void conv128_v2(const float* __restrict__ X,
    const float* __restrict__ WT, const float* __restrict__ Bv,
    float* __restrict__ Y) {
  __shared__ float xb[2][16][64];    // 8 KB
  __shared__ float wb[2][16][128];   // 16 KB
  const int t = threadIdx.x;
  const int p0 = blockIdx.x * 64;
  const int to = t >> 3;   // 0..15 -> outputs to*8..to*8+7
  const int tp = t & 7;    // 0..7  -> pixels  tp*8..tp*8+7

  float acc[8][8];
#pragma unroll
  for (int i = 0; i < 8; ++i) {
    const float b = Bv[to * 8 + i];
#pragma unroll
    for (int j = 0; j < 8; ++j) acc[i][j] = b;
  }

  // prologue: stage chunk 0
#pragma unroll
  for (int j = 0; j < 2; ++j) {
    const int idx = t + j * 128, k = idx >> 4, c = (idx & 15) * 4;
    *(float4*)(&xb[0][k][c]) = *(const float4*)(X + k * NPIX + p0 + c);
  }
#pragma unroll
  for (int j = 0; j < 4; ++j) {
    const int idx = t + j * 128, k = idx >> 5, c = (idx & 31) * 4;
    *(float4*)(&wb[0][k][c]) = *(const float4*)(WT + k * 128 + c);
  }
  __syncthreads();

  for (int ch = 0; ch < 8; ++ch) {
    const int cur = ch & 1, nxt = cur ^ 1;
    float4 xs[2], ws[4];
    const int k1 = (ch + 1) * 16;
    if (ch < 7) {
#pragma unroll
      for (int j = 0; j < 2; ++j) {
        const int idx = t + j * 128, k = idx >> 4, c = (idx & 15) * 4;
        xs[j] = *(const float4*)(X + (k1 + k) * NPIX + p0 + c);
      }
#pragma unroll
      for (int j = 0; j < 4; ++j) {
        const int idx = t + j * 128, k = idx >> 5, c = (idx & 31) * 4;
        ws[j] = *(const float4*)(WT + (k1 + k) * 128 + c);
      }
    }
#pragma unroll
    for (int k = 0; k < 16; ++k) {
      float xv[8], wv[8];
      *(float4*)&xv[0] = *(const float4*)(&xb[cur][k][tp * 8]);
      *(float4*)&xv[4] = *(const float4*)(&xb[cur][k][tp * 8 + 4]);
      *(float4*)&wv[0] = *(const float4*)(&wb[cur][k][to * 8]);
      *(float4*)&wv[4] = *(const float4*)(&wb[cur][k][to * 8 + 4]);
#pragma unroll
      for (int i = 0; i < 8; ++i)
#pragma unroll
        for (int j = 0; j < 8; ++j)
          acc[i][j] = fmaf(wv[i], xv[j], acc[i][j]);
    }
    __syncthreads();
    if (ch < 7) {
#pragma unroll
      for (int j = 0; j < 2; ++j) {
        const int idx = t + j * 128, k = idx >> 4, c = (idx & 15) * 4;
        *(float4*)(&xb[nxt][k][c]) = xs[j];
      }
#pragma unroll
      for (int j = 0; j < 4; ++j) {
        const int idx = t + j * 128, k = idx >> 5, c = (idx & 31) * 4;
        *(float4*)(&wb[nxt][k][c]) = ws[j];
      }
      __syncthreads();
    }
  }

#pragma unroll
  for (int i = 0; i < 8; ++i) {
    float4 v0, v1;
    float* p = (float*)&v0;
#pragma unroll
    for (int j = 0; j < 4; ++j) {
      float v = acc[i][j];
      if (ACT) v = v > 0.f ? v : 0.01f * v;
      p[j] = v;
    }
    p = (float*)&v1;
#pragma unroll
    for (int j = 0; j < 4; ++j) {
      float v = acc[i][4 + j];
      if (ACT) v = v > 0.f ? v : 0.01f * v;
      p[j] = v;
    }
    float* yrow = Y + (to * 8 + i) * NPIX + p0 + tp * 8;
    *(float4*)yrow = v0;
    *(float4*)(yrow + 4) = v1;
  }
}

// ---------------------------------------------------------------------------
// conv 128->17 + argmax(first 16) + mask = lrelu(ch 16). inds1 pixel-order.
// ---------------------------------------------------------------------------
__global__ __launch_bounds__(256) void conv17_k(const float* __restrict__ X,
    const float* __restrict__ W, const float* __restrict__ Bv,
    int* __restrict__ inds1, float* __restrict__ mask_out) {
  const int p = blockIdx.x * 256 + threadIdx.x;
  float acc[17];
#pragma unroll
  for (int o = 0; o < 17; ++o) acc[o] = Bv[o];
  for (int k0 = 0; k0 < 128; k0 += 8) {
    float xv[8];
#pragma unroll
    for (int kk = 0; kk < 8; ++kk) xv[kk] = X[(k0 + kk) * NPIX + p];
#pragma unroll
    for (int o = 0; o < 17; ++o) {
#pragma unroll
      for (int kk = 0; kk < 8; ++kk)
        acc[o] = fmaf(xv[kk], W[o * 128 + k0 + kk], acc[o]);
    }
  }
  int am = 0;
  float bv = acc[0];
#pragma unroll
  for (int o = 1; o < 16; ++o) {
    if (acc[o] > bv) { bv = acc[o]; am = o; }
  }
  inds1[p] = am;
  const float m = acc[16];
  mask_out[p] = m > 0.f ? m : 0.01f * m;
}

// ---------------------------------------------------------------------------
// transpose x[k][h][w] -> xt[(w*H+h)*128 + k]  (token-major feature rows)
// ---------------------------------------------------------------------------
__global__ __launch_bounds__(256) void transpose_k(const float* __restrict__ X,
                                                   float* __restrict__ xt) {
  __shared__ float tile[32][33];
  const int w0 = (blockIdx.x & 7) * 32;
  const int k0 = ((blockIdx.x >> 3) & 3) * 32;
  const int h  = blockIdx.x >> 5;
  const int t = threadIdx.x;
  const int c = t & 31, rr = t >> 5;
#pragma unroll
  for (int j = 0; j < 4; ++j) {
    const int k = rr + j * 8;
    tile[k][c] = X[(k0 + k) * NPIX + h * W_ + w0 + c];
  }
  __syncthreads();
#pragma unroll
  for (int j = 0; j < 4; ++j) {
    const int w = rr + j * 8;
    xt[((w0 + w) * H_ + h) * 128 + k0 + c] = tile[c][w];
  }
}

// ---------------------------------------------------------------------------
__global__ __launch_bounds__(256) void init_k(int* __restrict__ a, int na,
                                              int* __restrict__ b, int nb) {
  const int t = threadIdx.x;
  for (int i = t; i < na; i += 256) a[i] = 0;
  for (int i = t; i < nb; i += 256) b[i] = 0;
}

__global__ __launch_bounds__(256) void hist_k(const int* __restrict__ bins,
                                              int* __restrict__ cnt) {
  __shared__ int lh[256];
  const int t = threadIdx.x;
  lh[t] = 0;
  __syncthreads();
  atomicAdd(&lh[bins[blockIdx.x * 256 + t]], 1);
  __syncthreads();
  if (lh[t] > 0) atomicAdd(&cnt[t], lh[t]);
}

// parallel scan + descriptor emit (replaces serial thread-0 loop)
template<int NB>
__global__ __launch_bounds__(256) void scan_desc_k(const int* __restrict__ cnt,
    int* __restrict__ off, int* __restrict__ desc, int* __restrict__ ndesc) {
  const int t = threadIdx.x;
  const int lane = t & 63, wvi = t >> 6;
  __shared__ int wsumC[4], wsumD[4];
  const int c = (t < NB) ? cnt[t] : 0;
  const int nb = (c + TPB - 1) / TPB;
  int ic = c, id = nb;
  for (int d = 1; d < 64; d <<= 1) {
    const int uc = __shfl_up(ic, d, 64);
    const int ud = __shfl_up(id, d, 64);
    if (lane >= d) { ic += uc; id += ud; }
  }
  if (lane == 63) { wsumC[wvi] = ic; wsumD[wvi] = id; }
  __syncthreads();
  int bc = 0, bd = 0;
#pragma unroll
  for (int w2 = 0; w2 < 4; ++w2) {
    if (w2 < wvi) { bc += wsumC[w2]; bd += wsumD[w2]; }
  }
  ic += bc; id += bd;
  if (t < NB) {
    off[t] = ic - c;
    const int db = id - nb;
    for (int j = 0; j < nb; ++j) desc[db + j] = (t << 12) | j;
  }
  if (t == NB - 1) *ndesc = id;
}

// two-level scatter: block-local ranks + one global atomic per (block,bin)
__global__ __launch_bounds__(256) void scatter_k(const int* __restrict__ bins,
    const int* __restrict__ off, int* __restrict__ cursor,
    int* __restrict__ ord, int nbins) {
  __shared__ int lhist[256], lbase[256], lcur[256];
  const int t = threadIdx.x;
  const int n = blockIdx.x * 256 + t;
  if (t < nbins) { lhist[t] = 0; lcur[t] = 0; }
  __syncthreads();
  const int b = bins[n];
  atomicAdd(&lhist[b], 1);
  __syncthreads();
  if (t < nbins && lhist[t] > 0) lbase[t] = atomicAdd(&cursor[t], lhist[t]);
  __syncthreads();
  const int r = atomicAdd(&lcur[b], 1);
  ord[off[b] + lbase[b] + r] = n;
}

// ---------------------------------------------------------------------------
// chain1: uniform expert e1 per block (scalar weight loads). Computes e12,
// fused histogram into cnt2.
// ---------------------------------------------------------------------------
__global__ __launch_bounds__(64) void chain1_k(const float* __restrict__ xt,
    const int* __restrict__ ord1, const int* __restrict__ off1,
    const int* __restrict__ cnt1, const int* __restrict__ desc1,
    const int* __restrict__ nd1,
    const float* __restrict__ wc21, const float* __restrict__ bc21,
    const float* __restrict__ wc22, const float* __restrict__ bc22,
    const float* __restrict__ wc23, const float* __restrict__ bc23,
    int* __restrict__ e12a, int* __restrict__ cnt2) {
  if ((int)blockIdx.x >= *nd1) return;
  __shared__ int lh[16];
  const int de = desc1[blockIdx.x];
  const int e = de >> 12, chunk = de & 0xFFF;
  const int cnt = cnt1[e];
  const int pos = chunk * TPB + (int)threadIdx.x;
  const bool valid = pos < cnt;
  const int n = valid ? ord1[off1[e] + pos] : 0;
  if (threadIdx.x < 16) lh[threadIdx.x] = 0;
  __syncthreads();
  const float* __restrict__ xr = xt + n * 128;

  const float* __restrict__ W1 = wc21 + e * 4096;
  const float* __restrict__ B1 = bc21 + e * 32;
  float a[32];
#pragma unroll
  for (int o = 0; o < 32; ++o) a[o] = B1[o];
  for (int k0 = 0; k0 < 128; k0 += 8) {
    float x[8];
#pragma unroll
    for (int q = 0; q < 2; ++q) {
      const float4 v = ((const float4*)(xr + k0))[q];
      x[4*q] = v.x; x[4*q+1] = v.y; x[4*q+2] = v.z; x[4*q+3] = v.w;
    }
#pragma unroll
    for (int kk = 0; kk < 8; ++kk)
#pragma unroll
      for (int o = 0; o < 32; ++o)
        a[o] = fmaf(x[kk], W1[(k0 + kk) * 32 + o], a[o]);
  }
#pragma unroll
  for (int o = 0; o < 32; ++o) a[o] = a[o] > 0.f ? a[o] : 0.01f * a[o];

  const float* __restrict__ W2 = wc22 + e * 1024;
  const float* __restrict__ B2 = bc22 + e * 32;
  float b[32];
#pragma unroll
  for (int o = 0; o < 32; ++o) b[o] = B2[o];
#pragma unroll
  for (int i = 0; i < 32; ++i)
#pragma unroll
    for (int o = 0; o < 32; ++o)
      b[o] = fmaf(a[i], W2[i * 32 + o], b[o]);
#pragma unroll
  for (int o = 0; o < 32; ++o) b[o] = b[o] > 0.f ? b[o] : 0.01f * b[o];

  const float* __restrict__ W3 = wc23 + e * 512;
  const float* __restrict__ B3 = bc23 + e * 16;
  float s[16];
#pragma unroll
  for (int o = 0; o < 16; ++o) s[o] = B3[o];
#pragma unroll
  for (int i = 0; i < 32; ++i)
#pragma unroll
    for (int o = 0; o < 16; ++o)
      s[o] = fmaf(b[i], W3[i * 16 + o], s[o]);

  int e2 = 0;
  float bv = s[0];
#pragma unroll
  for (int o = 1; o < 16; ++o) {
    if (s[o] > bv) { bv = s[o]; e2 = o; }
  }
  const int e12 = e * 16 + e2;
  if (valid) {
    e12a[n] = e12;
    atomicAdd(&lh[e2], 1);
  }
  __syncthreads();
  if (threadIdx.x < 16 && lh[threadIdx.x] > 0)
    atomicAdd(&cnt2[e * 16 + threadIdx.x], lh[threadIdx.x]);
}

// ---------------------------------------------------------------------------
// chain2: uniform expert e12 per block. Writes out[n].
// ---------------------------------------------------------------------------
__global__ __launch_bounds__(64) void chain2_k(const float* __restrict__ xt,
    const int* __restrict__ ord2, const int* __restrict__ off2,
    const int* __restrict__ cnt2, const int* __restrict__ desc2,
    const int* __restrict__ nd2,
    const float* __restrict__ wr11, const float* __restrict__ br11,
    const float* __restrict__ wr12, const float* __restrict__ br12,
    const float* __restrict__ wr13, const float* __restrict__ br13,
    float* __restrict__ out) {
  if ((int)blockIdx.x >= *nd2) return;
  const int de = desc2[blockIdx.x];
  const int e12 = de >> 12, chunk = de & 0xFFF;
  const int cnt = cnt2[e12];
  const int pos = chunk * TPB + (int)threadIdx.x;
  const bool valid = pos < cnt;
  const int n = valid ? ord2[off2[e12] + pos] : 0;
  const float* __restrict__ xr = xt + n * 128;

  const float* __restrict__ W1 = wr11 + e12 * 4096;
  const float* __restrict__ B1 = br11 + e12 * 32;
  float a[32];
#pragma unroll
  for (int o = 0; o < 32; ++o) a[o] = B1[o];
  for (int k0 = 0; k0 < 128; k0 += 8) {
    float x[8];
#pragma unroll
    for (int q = 0; q < 2; ++q) {
      const float4 v = ((const float4*)(xr + k0))[q];
      x[4*q] = v.x; x[4*q+1] = v.y; x[4*q+2] = v.z; x[4*q+3] = v.w;
    }
#pragma unroll
    for (int kk = 0; kk < 8; ++kk)
#pragma unroll
      for (int o = 0; o < 32; ++o)
        a[o] = fmaf(x[kk], W1[(k0 + kk) * 32 + o], a[o]);
  }
#pragma unroll
  for (int o = 0; o < 32; ++o) a[o] = a[o] > 0.f ? a[o] : 0.01f * a[o];

  const float* __restrict__ W2 = wr12 + e12 * 512;
  const float* __restrict__ B2 = br12 + e12 * 16;
  float s[16];
#pragma unroll
  for (int o = 0; o < 16; ++o) s[o] = B2[o];
#pragma unroll
  for (int i = 0; i < 32; ++i)
#pragma unroll
    for (int o = 0; o < 16; ++o)
      s[o] = fmaf(a[i], W2[i * 16 + o], s[o]);
#pragma unroll
  for (int o = 0; o < 16; ++o) s[o] = s[o] > 0.f ? s[o] : 0.01f * s[o];

  float r = br13[e12];
  const float* __restrict__ W3 = wr13 + e12 * 16;
#pragma unroll
  for (int i = 0; i < 16; ++i) r = fmaf(s[i], W3[i], r);

  if (valid) out[n] = ((float)e12 + r) * (1.0f / 256.0f);
}

// ---------------------------------------------------------------------------
extern "C" void kernel_launch(void* const* d_in, const int* in_sizes, int n_in,
                              void* d_out, int out_size, void* d_ws,
                              size_t ws_size, hipStream_t stream) {
  const float* x_in  = (const float*)d_in[0];
  const float* w_c11 = (const float*)d_in[1];
  const float* b_c11 = (const float*)d_in[2];
  const float* w_c12 = (const float*)d_in[3];
  const float* b_c12 = (const float*)d_in[4];
  const float* w_c13 = (const float*)d_in[5];
  const float* b_c13 = (const float*)d_in[6];
  const float* w_c21 = (const float*)d_in[7];
  const float* b_c21 = (const float*)d_in[8];
  const float* w_c22 = (const float*)d_in[9];
  const float* b_c22 = (const float*)d_in[10];
  const float* w_c23 = (const float*)d_in[11];
  const float* b_c23 = (const float*)d_in[12];
  const float* w_r11 = (const float*)d_in[13];
  const float* b_r11 = (const float*)d_in[14];
  const float* w_r12 = (const float*)d_in[15];
  const float* b_r12 = (const float*)d_in[16];
  const float* w_r13 = (const float*)d_in[17];
  const float* b_r13 = (const float*)d_in[18];

  float* out = (float*)d_out;   // [0..N): x_real (token order), [N..2N): mask

  // ws regions (within proven 50.5 MB footprint):
  //   R0 = 128N floats : conv1 out, then xt
  //   R1 = 128N floats : conv2 out, then int binning scratch
  //   R2 = N ints      : wT1+wT2 during convs, then inds1
  float* R0 = (float*)d_ws;
  float* R1 = R0 + 128 * NPIX;
  int*   R2 = (int*)(R1 + 128 * NPIX);

  float* y1 = R0;
  float* y2 = R1;
  float* xt = R0;                      // alias after conv2 reads R0
  float* wT1 = (float*)R2;             // 16384 floats
  float* wT2 = wT1 + 16384;            // 16384 floats (total 128KB <= N ints)
  int* inds1 = R2;                     // after wT dead

  int* ib    = (int*)R1;               // after conv17 reads R1
  int* ord1  = ib;                     // N
  int* ord2  = ib + NPIX;              // N
  int* e12a  = ib + 2 * NPIX;          // N
  int* cnt1  = ib + 3 * NPIX;          // 16
  int* cur1  = cnt1 + 16;              // 16
  int* off1  = cur1 + 16;              // 16
  int* nd1   = off1 + 16;              // 1 (+pad)
  int* desc1 = nd1 + 16;               // 1024
  int* cnt2  = desc1 + 1024;           // 256
  int* cur2  = cnt2 + 256;             // 256
  int* off2  = cur2 + 256;             // 256
  int* nd2   = off2 + 256;             // 1 (+pad)
  int* desc2 = nd2 + 16;               // 1024

  wtrans_k<<<16, 256, 0, stream>>>(w_c11, wT1);
  wtrans_k<<<16, 256, 0, stream>>>(w_c12, wT2);
  conv128_v2<true><<<NPIX / 64, 128, 0, stream>>>(x_in, wT1, b_c11, y1);
  conv128_v2<true><<<NPIX / 64, 128, 0, stream>>>(y1, wT2, b_c12, y2);
  conv17_k<<<NPIX / 256, 256, 0, stream>>>(y2, w_c13, b_c13, inds1, out + NPIX);

  // R0 free (conv2 consumed it) -> xt; R1 free (conv17 consumed it) -> ints
  transpose_k<<<192 * 32, 256, 0, stream>>>(x_in, xt);
  init_k<<<1, 256, 0, stream>>>(cnt1, 32, cnt2, 512);
  hist_k<<<NPIX / 256, 256, 0, stream>>>(inds1, cnt1);
  scan_desc_k<16><<<1, 256, 0, stream>>>(cnt1, off1, desc1, nd1);
  scatter_k<<<NPIX / 256, 256, 0, stream>>>(inds1, off1, cur1, ord1, 16);
  chain1_k<<<NPIX / TPB + 16, TPB, 0, stream>>>(xt, ord1, off1, cnt1, desc1, nd1,
      w_c21, b_c21, w_c22, b_c22, w_c23, b_c23, e12a, cnt2);
  scan_desc_k<256><<<1, 256, 0, stream>>>(cnt2, off2, desc2, nd2);
  scatter_k<<<NPIX / 256, 256, 0, stream>>>(e12a, off2, cur2, ord2, 256);
  chain2_k<<<NPIX / TPB + 256, TPB, 0, stream>>>(xt, ord2, off2, cnt2, desc2, nd2,
      w_r11, b_r11, w_r12, b_r12, w_r13, b_r13, out);
}

// Round 4
// 210.488 us; speedup vs baseline: 2.2346x; 1.2421x over previous
//
#include <hip/hip_runtime.h>

#define NPIX 49152   // B*H*W = 1*192*256
#define H_ 192
#define W_ 256
#define TPB 64       // tokens per chain block (1 wave)

// W-tile bank swizzle: col' = col + (col>>5)*4  (keeps float4 alignment;
// makes the 16 distinct ds_read_b128 addresses per wave exactly 2-way)
#define WSWZ(c) ((c) + (((c) >> 5) << 2))

// ---------------------------------------------------------------------------
// both weight transposes (32 blocks) + zero binning counters (block 0)
// ---------------------------------------------------------------------------
__global__ __launch_bounds__(256) void wtrans2_k(const float* __restrict__ Wa,
    float* __restrict__ WTa, const float* __restrict__ Wb,
    float* __restrict__ WTb, int* __restrict__ S) {
  const int b = blockIdx.x;
  const float* __restrict__ W = (b < 16) ? Wa : Wb;
  float* __restrict__ WT = (b < 16) ? WTa : WTb;
  const int bb = b & 15;
  __shared__ float tile[32][33];
  const int bx = bb & 3, by = bb >> 2;
  const int c = threadIdx.x & 31, r0 = threadIdx.x >> 5;
#pragma unroll
  for (int j = 0; j < 4; ++j) {
    const int r = r0 + j * 8;
    tile[r][c] = W[(by * 32 + r) * 128 + bx * 32 + c];
  }
  __syncthreads();
#pragma unroll
  for (int j = 0; j < 4; ++j) {
    const int r = r0 + j * 8;
    WT[(bx * 32 + r) * 128 + by * 32 + c] = tile[c][r];
  }
  if (b == 0) {
    const int t = threadIdx.x;
    if (t < 32) S[t] = 0;        // cnt1 + cur1
    S[1088 + t] = 0;             // cnt2
    S[1344 + t] = 0;             // cur2
  }
}

// ---------------------------------------------------------------------------
// conv 128->128 as register-blocked GEMM.
// Block: 128 threads (2 waves), tile 128 outputs x 32 pixels, micro 8x4.
// 1536 blocks -> 6 blocks/CU -> 3 waves/SIMD. Double-buffered K=16 chunks.
// Accumulation: bias then k ascending — bitwise-identical to prior rounds.
// ---------------------------------------------------------------------------
template<bool ACT>
__global__ __launch_bounds__(128) void conv128_v3(const float* __restrict__ X,
    const float* __restrict__ WT, const float* __restrict__ Bv,
    float* __restrict__ Y) {
  __shared__ float xb[2][16][32];    // 4 KB
  __shared__ float wb[2][16][140];   // 17.9 KB (swizzled cols, max 139)
  const int t = threadIdx.x;
  const int p0 = blockIdx.x * 32;
  const int to = t >> 3;                 // 0..15 -> outputs to*8..to*8+7
  const int tp = t & 7;                  // 0..7  -> pixels  tp*4..tp*4+3
  const int wcol = WSWZ(to * 8);         // swizzled W read base

  float acc[8][4];
#pragma unroll
  for (int i = 0; i < 8; ++i) {
    const float b = Bv[to * 8 + i];
#pragma unroll
    for (int j = 0; j < 4; ++j) acc[i][j] = b;
  }

  // prologue: stage chunk 0
  {
    const int k = t >> 3, c = (t & 7) * 4;
    *(float4*)(&xb[0][k][c]) = *(const float4*)(X + k * NPIX + p0 + c);
  }
#pragma unroll
  for (int j = 0; j < 4; ++j) {
    const int idx = t + j * 128, k = idx >> 5, c = (idx & 31) * 4;
    *(float4*)(&wb[0][k][WSWZ(c)]) = *(const float4*)(WT + k * 128 + c);
  }
  __syncthreads();

  for (int ch = 0; ch < 8; ++ch) {
    const int cur = ch & 1, nxt = cur ^ 1;
    float4 xs, ws[4];
    const int k1 = (ch + 1) * 16;
    if (ch < 7) {
      {
        const int k = t >> 3, c = (t & 7) * 4;
        xs = *(const float4*)(X + (k1 + k) * NPIX + p0 + c);
      }
#pragma unroll
      for (int j = 0; j < 4; ++j) {
        const int idx = t + j * 128, k = idx >> 5, c = (idx & 31) * 4;
        ws[j] = *(const float4*)(WT + (k1 + k) * 128 + c);
      }
    }
#pragma unroll
    for (int k = 0; k < 16; ++k) {
      float xv[4], wv[8];
      *(float4*)&xv[0] = *(const float4*)(&xb[cur][k][tp * 4]);
      *(float4*)&wv[0] = *(const float4*)(&wb[cur][k][wcol]);
      *(float4*)&wv[4] = *(const float4*)(&wb[cur][k][wcol + 4]);
#pragma unroll
      for (int i = 0; i < 8; ++i)
#pragma unroll
        for (int j = 0; j < 4; ++j)
          acc[i][j] = fmaf(wv[i], xv[j], acc[i][j]);
    }
    __syncthreads();
    if (ch < 7) {
      {
        const int k = t >> 3, c = (t & 7) * 4;
        *(float4*)(&xb[nxt][k][c]) = xs;
      }
#pragma unroll
      for (int j = 0; j < 4; ++j) {
        const int idx = t + j * 128, k = idx >> 5, c = (idx & 31) * 4;
        *(float4*)(&wb[nxt][k][WSWZ(c)]) = ws[j];
      }
      __syncthreads();
    }
  }

#pragma unroll
  for (int i = 0; i < 8; ++i) {
    float4 v;
    float* pv = (float*)&v;
#pragma unroll
    for (int j = 0; j < 4; ++j) {
      float x = acc[i][j];
      if (ACT) x = x > 0.f ? x : 0.01f * x;
      pv[j] = x;
    }
    *(float4*)(Y + (to * 8 + i) * NPIX + p0 + tp * 4) = v;
  }
}

// ---------------------------------------------------------------------------
// conv 128->17 + argmax(first 16) + mask + fused inds1 histogram.
// ---------------------------------------------------------------------------
__global__ __launch_bounds__(256) void conv17_k(const float* __restrict__ X,
    const float* __restrict__ W, const float* __restrict__ Bv,
    unsigned char* __restrict__ inds1, float* __restrict__ mask_out,
    int* __restrict__ cnt1) {
  __shared__ int lh[16];
  const int t = threadIdx.x;
  if (t < 16) lh[t] = 0;
  __syncthreads();
  const int p = blockIdx.x * 256 + t;
  float acc[17];
#pragma unroll
  for (int o = 0; o < 17; ++o) acc[o] = Bv[o];
  for (int k0 = 0; k0 < 128; k0 += 8) {
    float xv[8];
#pragma unroll
    for (int kk = 0; kk < 8; ++kk) xv[kk] = X[(k0 + kk) * NPIX + p];
#pragma unroll
    for (int o = 0; o < 17; ++o) {
#pragma unroll
      for (int kk = 0; kk < 8; ++kk)
        acc[o] = fmaf(xv[kk], W[o * 128 + k0 + kk], acc[o]);
    }
  }
  int am = 0;
  float bv = acc[0];
#pragma unroll
  for (int o = 1; o < 16; ++o) {
    if (acc[o] > bv) { bv = acc[o]; am = o; }
  }
  inds1[p] = (unsigned char)am;
  const float m = acc[16];
  mask_out[p] = m > 0.f ? m : 0.01f * m;
  atomicAdd(&lh[am], 1);
  __syncthreads();
  if (t < 16 && lh[t] > 0) atomicAdd(&cnt1[t], lh[t]);
}

// ---------------------------------------------------------------------------
// transpose x[k][h][w] -> xt[(w*H+h)*128 + k]  (token-major feature rows)
// ---------------------------------------------------------------------------
__global__ __launch_bounds__(256) void transpose_k(const float* __restrict__ X,
                                                   float* __restrict__ xt) {
  __shared__ float tile[32][33];
  const int w0 = (blockIdx.x & 7) * 32;
  const int k0 = ((blockIdx.x >> 3) & 3) * 32;
  const int h  = blockIdx.x >> 5;
  const int t = threadIdx.x;
  const int c = t & 31, rr = t >> 5;
#pragma unroll
  for (int j = 0; j < 4; ++j) {
    const int k = rr + j * 8;
    tile[k][c] = X[(k0 + k) * NPIX + h * W_ + w0 + c];
  }
  __syncthreads();
#pragma unroll
  for (int j = 0; j < 4; ++j) {
    const int w = rr + j * 8;
    xt[((w0 + w) * H_ + h) * 128 + k0 + c] = tile[c][w];
  }
}

// parallel scan + descriptor emit
template<int NB>
__global__ __launch_bounds__(256) void scan_desc_k(const int* __restrict__ cnt,
    int* __restrict__ off, int* __restrict__ desc, int* __restrict__ ndesc) {
  const int t = threadIdx.x;
  const int lane = t & 63, wvi = t >> 6;
  __shared__ int wsumC[4], wsumD[4];
  const int c = (t < NB) ? cnt[t] : 0;
  const int nb = (c + TPB - 1) / TPB;
  int ic = c, id = nb;
  for (int d = 1; d < 64; d <<= 1) {
    const int uc = __shfl_up(ic, d, 64);
    const int ud = __shfl_up(id, d, 64);
    if (lane >= d) { ic += uc; id += ud; }
  }
  if (lane == 63) { wsumC[wvi] = ic; wsumD[wvi] = id; }
  __syncthreads();
  int bc = 0, bd = 0;
#pragma unroll
  for (int w2 = 0; w2 < 4; ++w2) {
    if (w2 < wvi) { bc += wsumC[w2]; bd += wsumD[w2]; }
  }
  ic += bc; id += bd;
  if (t < NB) {
    off[t] = ic - c;
    const int db = id - nb;
    for (int j = 0; j < nb; ++j) desc[db + j] = (t << 12) | j;
  }
  if (t == NB - 1) *ndesc = id;
}

// two-level scatter: block-local ranks + one global atomic per (block,bin)
template<typename T>
__global__ __launch_bounds__(256) void scatter_k(const T* __restrict__ bins,
    const int* __restrict__ off, int* __restrict__ cursor,
    int* __restrict__ ord, int nbins) {
  __shared__ int lhist[256], lbase[256], lcur[256];
  const int t = threadIdx.x;
  const int n = blockIdx.x * 256 + t;
  if (t < nbins) { lhist[t] = 0; lcur[t] = 0; }
  __syncthreads();
  const int b = (int)bins[n];
  atomicAdd(&lhist[b], 1);
  __syncthreads();
  if (t < nbins && lhist[t] > 0) lbase[t] = atomicAdd(&cursor[t], lhist[t]);
  __syncthreads();
  const int r = atomicAdd(&lcur[b], 1);
  ord[off[b] + lbase[b] + r] = n;
}

// ---------------------------------------------------------------------------
// chain1: uniform expert e1 per block (scalar weight loads). Computes e12,
// fused histogram into cnt2.
// ---------------------------------------------------------------------------
__global__ __launch_bounds__(64) void chain1_k(const float* __restrict__ xt,
    const int* __restrict__ ord1, const int* __restrict__ off1,
    const int* __restrict__ cnt1, const int* __restrict__ desc1,
    const int* __restrict__ nd1,
    const float* __restrict__ wc21, const float* __restrict__ bc21,
    const float* __restrict__ wc22, const float* __restrict__ bc22,
    const float* __restrict__ wc23, const float* __restrict__ bc23,
    int* __restrict__ e12a, int* __restrict__ cnt2) {
  if ((int)blockIdx.x >= *nd1) return;
  __shared__ int lh[16];
  const int de = desc1[blockIdx.x];
  const int e = de >> 12, chunk = de & 0xFFF;
  const int cnt = cnt1[e];
  const int pos = chunk * TPB + (int)threadIdx.x;
  const bool valid = pos < cnt;
  const int n = valid ? ord1[off1[e] + pos] : 0;
  if (threadIdx.x < 16) lh[threadIdx.x] = 0;
  __syncthreads();
  const float* __restrict__ xr = xt + n * 128;

  const float* __restrict__ W1 = wc21 + e * 4096;
  const float* __restrict__ B1 = bc21 + e * 32;
  float a[32];
#pragma unroll
  for (int o = 0; o < 32; ++o) a[o] = B1[o];
  for (int k0 = 0; k0 < 128; k0 += 8) {
    float x[8];
#pragma unroll
    for (int q = 0; q < 2; ++q) {
      const float4 v = ((const float4*)(xr + k0))[q];
      x[4*q] = v.x; x[4*q+1] = v.y; x[4*q+2] = v.z; x[4*q+3] = v.w;
    }
#pragma unroll
    for (int kk = 0; kk < 8; ++kk)
#pragma unroll
      for (int o = 0; o < 32; ++o)
        a[o] = fmaf(x[kk], W1[(k0 + kk) * 32 + o], a[o]);
  }
#pragma unroll
  for (int o = 0; o < 32; ++o) a[o] = a[o] > 0.f ? a[o] : 0.01f * a[o];

  const float* __restrict__ W2 = wc22 + e * 1024;
  const float* __restrict__ B2 = bc22 + e * 32;
  float b[32];
#pragma unroll
  for (int o = 0; o < 32; ++o) b[o] = B2[o];
#pragma unroll
  for (int i = 0; i < 32; ++i)
#pragma unroll
    for (int o = 0; o < 32; ++o)
      b[o] = fmaf(a[i], W2[i * 32 + o], b[o]);
#pragma unroll
  for (int o = 0; o < 32; ++o) b[o] = b[o] > 0.f ? b[o] : 0.01f * b[o];

  const float* __restrict__ W3 = wc23 + e * 512;
  const float* __restrict__ B3 = bc23 + e * 16;
  float s[16];
#pragma unroll
  for (int o = 0; o < 16; ++o) s[o] = B3[o];
#pragma unroll
  for (int i = 0; i < 32; ++i)
#pragma unroll
    for (int o = 0; o < 16; ++o)
      s[o] = fmaf(b[i], W3[i * 16 + o], s[o]);

  int e2 = 0;
  float bv = s[0];
#pragma unroll
  for (int o = 1; o < 16; ++o) {
    if (s[o] > bv) { bv = s[o]; e2 = o; }
  }
  const int e12 = e * 16 + e2;
  if (valid) {
    e12a[n] = e12;
    atomicAdd(&lh[e2], 1);
  }
  __syncthreads();
  if (threadIdx.x < 16 && lh[threadIdx.x] > 0)
    atomicAdd(&cnt2[e * 16 + threadIdx.x], lh[threadIdx.x]);
}

// ---------------------------------------------------------------------------
// chain2: uniform expert e12 per block. Writes out[n].
// ---------------------------------------------------------------------------
__global__ __launch_bounds__(64) void chain2_k(const float* __restrict__ xt,
    const int* __restrict__ ord2, const int* __restrict__ off2,
    const int* __restrict__ cnt2, const int* __restrict__ desc2,
    const int* __restrict__ nd2,
    const float* __restrict__ wr11, const float* __restrict__ br11,
    const float* __restrict__ wr12, const float* __restrict__ br12,
    const float* __restrict__ wr13, const float* __restrict__ br13,
    float* __restrict__ out) {
  if ((int)blockIdx.x >= *nd2) return;
  const int de = desc2[blockIdx.x];
  const int e12 = de >> 12, chunk = de & 0xFFF;
  const int cnt = cnt2[e12];
  const int pos = chunk * TPB + (int)threadIdx.x;
  const bool valid = pos < cnt;
  const int n = valid ? ord2[off2[e12] + pos] : 0;
  const float* __restrict__ xr = xt + n * 128;

  const float* __restrict__ W1 = wr11 + e12 * 4096;
  const float* __restrict__ B1 = br11 + e12 * 32;
  float a[32];
#pragma unroll
  for (int o = 0; o < 32; ++o) a[o] = B1[o];
  for (int k0 = 0; k0 < 128; k0 += 8) {
    float x[8];
#pragma unroll
    for (int q = 0; q < 2; ++q) {
      const float4 v = ((const float4*)(xr + k0))[q];
      x[4*q] = v.x; x[4*q+1] = v.y; x[4*q+2] = v.z; x[4*q+3] = v.w;
    }
#pragma unroll
    for (int kk = 0; kk < 8; ++kk)
#pragma unroll
      for (int o = 0; o < 32; ++o)
        a[o] = fmaf(x[kk], W1[(k0 + kk) * 32 + o], a[o]);
  }
#pragma unroll
  for (int o = 0; o < 32; ++o) a[o] = a[o] > 0.f ? a[o] : 0.01f * a[o];

  const float* __restrict__ W2 = wr12 + e12 * 512;
  const float* __restrict__ B2 = br12 + e12 * 16;
  float s[16];
#pragma unroll
  for (int o = 0; o < 16; ++o) s[o] = B2[o];
#pragma unroll
  for (int i = 0; i < 32; ++i)
#pragma unroll
    for (int o = 0; o < 16; ++o)
      s[o] = fmaf(a[i], W2[i * 16 + o], s[o]);
#pragma unroll
  for (int o = 0; o < 16; ++o) s[o] = s[o] > 0.f ? s[o] : 0.01f * s[o];

  float r = br13[e12];
  const float* __restrict__ W3 = wr13 + e12 * 16;
#pragma unroll
  for (int i = 0; i < 16; ++i) r = fmaf(s[i], W3[i], r);

  if (valid) out[n] = ((float)e12 + r) * (1.0f / 256.0f);
}

// ---------------------------------------------------------------------------
extern "C" void kernel_launch(void* const* d_in, const int* in_sizes, int n_in,
                              void* d_out, int out_size, void* d_ws,
                              size_t ws_size, hipStream_t stream) {
  const float* x_in  = (const float*)d_in[0];
  const float* w_c11 = (const float*)d_in[1];
  const float* b_c11 = (const float*)d_in[2];
  const float* w_c12 = (const float*)d_in[3];
  const float* b_c12 = (const float*)d_in[4];
  const float* w_c13 = (const float*)d_in[5];
  const float* b_c13 = (const float*)d_in[6];
  const float* w_c21 = (const float*)d_in[7];
  const float* b_c21 = (const float*)d_in[8];
  const float* w_c22 = (const float*)d_in[9];
  const float* b_c22 = (const float*)d_in[10];
  const float* w_c23 = (const float*)d_in[11];
  const float* b_c23 = (const float*)d_in[12];
  const float* w_r11 = (const float*)d_in[13];
  const float* b_r11 = (const float*)d_in[14];
  const float* w_r12 = (const float*)d_in[15];
  const float* b_r12 = (const float*)d_in[16];
  const float* w_r13 = (const float*)d_in[17];
  const float* b_r13 = (const float*)d_in[18];

  float* out = (float*)d_out;   // [0..N): x_real (token order), [N..2N): mask

  // ws regions (within proven 50.5 MB footprint):
  //   R0 = 128N floats : conv1 out, then xt
  //   R1 = 128N floats : conv2 out, then ord1/ord2/e12a ints
  //   R2 = N floats    : inds1_u8 (48KB) | wT1 | wT2 | smalls S (12KB)
  float* R0 = (float*)d_ws;
  float* R1 = R0 + 128 * NPIX;
  float* R2 = R1 + 128 * NPIX;

  float* y1 = R0;
  float* y2 = R1;
  float* xt = R0;                          // alias after conv2 reads R0
  unsigned char* inds1 = (unsigned char*)R2;   // N bytes
  float* wT1 = R2 + 12288;                 // 16384 floats
  float* wT2 = wT1 + 16384;                // 16384 floats
  int* S = (int*)R2 + 45056;               // 2896 ints of smalls (4096 avail)

  int* cnt1  = S;            // 16
  int* cur1  = S + 16;       // 16
  int* off1  = S + 32;       // 16
  int* nd1   = S + 48;       // 1 (+pad)
  int* desc1 = S + 64;       // 1024
  int* cnt2  = S + 1088;     // 256
  int* cur2  = S + 1344;     // 256
  int* off2  = S + 1600;     // 256
  int* nd2   = S + 1856;     // 1 (+pad)
  int* desc2 = S + 1872;     // 1024

  int* ib   = (int*)R1;      // after conv17 reads R1
  int* ord1 = ib;            // N
  int* ord2 = ib + NPIX;     // N
  int* e12a = ib + 2 * NPIX; // N

  wtrans2_k<<<32, 256, 0, stream>>>(w_c11, wT1, w_c12, wT2, S);
  conv128_v3<true><<<NPIX / 32, 128, 0, stream>>>(x_in, wT1, b_c11, y1);
  conv128_v3<true><<<NPIX / 32, 128, 0, stream>>>(y1, wT2, b_c12, y2);
  transpose_k<<<192 * 32, 256, 0, stream>>>(x_in, xt);   // R0 free after conv2
  conv17_k<<<NPIX / 256, 256, 0, stream>>>(y2, w_c13, b_c13, inds1,
                                           out + NPIX, cnt1);
  scan_desc_k<16><<<1, 256, 0, stream>>>(cnt1, off1, desc1, nd1);
  scatter_k<unsigned char><<<NPIX / 256, 256, 0, stream>>>(inds1, off1, cur1,
                                                           ord1, 16);
  chain1_k<<<NPIX / TPB + 16, TPB, 0, stream>>>(xt, ord1, off1, cnt1, desc1,
      nd1, w_c21, b_c21, w_c22, b_c22, w_c23, b_c23, e12a, cnt2);
  scan_desc_k<256><<<1, 256, 0, stream>>>(cnt2, off2, desc2, nd2);
  scatter_k<int><<<NPIX / 256, 256, 0, stream>>>(e12a, off2, cur2, ord2, 256);
  chain2_k<<<NPIX / TPB + 256, TPB, 0, stream>>>(xt, ord2, off2, cnt2, desc2,
      nd2, w_r11, b_r11, w_r12, b_r12, w_r13, b_r13, out);
}